// Round 9
// baseline (44.834 us; speedup 1.0000x reference)
//
#include <hip/hip_runtime.h>
#include <hip/hip_bf16.h>

// MyDeConv1D as GEMM: out[b,t,f] = sum_{j,c} x[b,t+28-4j,c]*W[c,j,f] + cnt(t)*256*bias[f]
// M=32768, N=256, K=2048, bf16 MFMA 16x16x32.
// R9: block-broadcast B. Block = 256 rows x 64 f (4 waves stacked on M, W_m=4),
//     so ALL waves read the SAME B frag per step -> unique B traffic 512->128MB,
//     L1 serves 3 of 4 waves. Grid 512 = 8t x 16b x 4ft, id = ft*128+tb so the
//     4 ft-blocks of one (t,b) tile share id%8 -> same XCD -> x fetched once/L2.
//     8 chunks of 32ch, LDS 2x17.8KB, slot=q^(row&3) swizzle (2-way = free).

#define B_    16
#define T_    2048
#define C_    256
#define KT    8
#define F_    256
#define SH    28
#define BT    256
#define FW    64
#define ROWS  (BT + SH)        // 284
#define CH    32               // channels per chunk
#define CHW   (ROWS * CH)      // 9088 ushorts per buffer (284 rows x 64B)
#define NTASK (ROWS * 4)       // 1136 16B-granule staging tasks per chunk

typedef __attribute__((ext_vector_type(8))) short short8;
typedef __attribute__((ext_vector_type(4))) float floatx4;

// Wf frag order: fid = S*16 + g, S = cs*8 + j (cs: 32-ch chunk, j: tap).
// frag (S,g): lane(l16,q) holds B[k=q*8+i][f=g*16+l16], c = cs*32 + q*8 + i.
// 1KB/frag, coalesced producer & consumer.
__global__ __launch_bounds__(256) void wprep_kernel(const float* __restrict__ W,
                                                    ushort* __restrict__ Wf) {
    const int tid  = threadIdx.x;
    const int fid  = blockIdx.x * 4 + (tid >> 6);   // 0..1023
    const int lane = tid & 63;
    const int g    = fid & 15;
    const int S    = fid >> 4;
    const int j    = S & 7, cs = S >> 3;
    const int c0   = cs * 32 + (lane >> 4) * 8;
    const int f    = g * 16 + (lane & 15);
    short8 pk;
    #pragma unroll
    for (int i = 0; i < 8; ++i) {
        __hip_bfloat16 h = __float2bfloat16(W[((c0 + i) * KT + j) * F_ + f]);
        pk[i] = *reinterpret_cast<const short*>(&h);
    }
    *reinterpret_cast<short8*>(Wf + (size_t)fid * 512 + lane * 8) = pk;
}

__device__ inline short8 cvt8(float4 a, float4 b) {
    float v[8] = {a.x, a.y, a.z, a.w, b.x, b.y, b.z, b.w};
    short8 r;
    #pragma unroll
    for (int i = 0; i < 8; ++i) {
        __hip_bfloat16 h = __float2bfloat16(v[i]);
        r[i] = *reinterpret_cast<const short*>(&h);
    }
    return r;
}

__global__ __launch_bounds__(256, 2) void deconv_kernel(
        const float* __restrict__ x, const ushort* __restrict__ Wf,
        const float* __restrict__ bias, float* __restrict__ out) {
    __shared__ ushort xs[2 * CHW];                  // 35.5 KiB
    const int bid  = blockIdx.x;
    const int ft   = bid >> 7;                      // f-tile 0..3
    const int tb   = bid & 127;
    const int b    = tb >> 3;
    const int t0   = (tb & 7) * BT;
    const int tid  = threadIdx.x;
    const int lane = tid & 63, w = tid >> 6;        // wave owns rows [w*64, w*64+64)
    const int l16  = lane & 15, q = lane >> 4;

    // staging: NTASK granule tasks (row=task>>2, g=task&3 -> 8 channels), 5 rounds.
    float4 SA[5], SB[5];

#define STAGE_LOAD(cs_) do {                                                   \
        _Pragma("unroll")                                                      \
        for (int k = 0; k < 5; ++k) {                                          \
            const int task = tid + k * 256;                                    \
            const int row_ = task >> 2, g_ = task & 3;                         \
            SA[k] = make_float4(0.f, 0.f, 0.f, 0.f);                           \
            SB[k] = make_float4(0.f, 0.f, 0.f, 0.f);                           \
            if (task < NTASK && t0 + row_ < T_) {                              \
                const float4* p_ = reinterpret_cast<const float4*>(            \
                    x + ((size_t)(b * T_ + t0 + row_) * C_ +                   \
                         (cs_) * CH + g_ * 8));                                \
                SA[k] = p_[0]; SB[k] = p_[1];                                  \
            } } } while (0)

#define STAGE_WRITE(buf_) do {                                                 \
        ushort* d_ = xs + (buf_) * CHW;                                        \
        _Pragma("unroll")                                                      \
        for (int k = 0; k < 5; ++k) {                                          \
            const int task = tid + k * 256;                                    \
            const int row_ = task >> 2, g_ = task & 3;                         \
            if (task < NTASK)                                                  \
                *reinterpret_cast<short8*>(                                    \
                    d_ + row_ * CH + ((g_ ^ (row_ & 3)) * 8)) =                \
                    cvt8(SA[k], SB[k]);                                        \
        } } while (0)

    // A frag (tap j, frag mf): row = SH-4j + w*64 + mf*16 + l16 (max 283),
    // logical slot q, physical = q ^ (row&3).
#define LOAD_A(buf_, j_, arr) do {                                             \
        const int rb_ = SH - 4 * (j_) + w * 64 + l16;                          \
        _Pragma("unroll")                                                      \
        for (int mf = 0; mf < 4; ++mf) {                                       \
            const int row_ = rb_ + mf * 16;                                    \
            arr[mf] = *reinterpret_cast<const short8*>(                        \
                xs + (buf_) * CHW + row_ * CH + ((q ^ (row_ & 3)) * 8));       \
        } } while (0)

#define LOAD_B(S_, arr) do {                                                   \
        const ushort* p_ = wbase + (size_t)(S_) * 8192;                        \
        _Pragma("unroll")                                                      \
        for (int nf = 0; nf < 4; ++nf)                                         \
            arr[nf] = *reinterpret_cast<const short8*>(p_ + nf * 512);         \
        } while (0)

#define DO_MFMA(aa, bb) do {                                                   \
        _Pragma("unroll")                                                      \
        for (int mf = 0; mf < 4; ++mf)                                         \
            _Pragma("unroll")                                                  \
            for (int nf = 0; nf < 4; ++nf)                                     \
                acc[mf][nf] = __builtin_amdgcn_mfma_f32_16x16x32_bf16(         \
                    aa[mf], bb[nf], acc[mf][nf], 0, 0, 0);                     \
        } while (0)

    // all 4 waves share the same wbase -> block-broadcast B (L1 reuse)
    const ushort* wbase = Wf + (size_t)(ft * 4) * 512 + lane * 8;

    float bf4[4];
    #pragma unroll
    for (int nf = 0; nf < 4; ++nf) bf4[nf] = bias[ft * 64 + nf * 16 + l16];

    floatx4 acc[4][4];
    #pragma unroll
    for (int mf = 0; mf < 4; ++mf)
        #pragma unroll
        for (int nf = 0; nf < 4; ++nf)
            acc[mf][nf] = (floatx4){0.f, 0.f, 0.f, 0.f};

    short8 aA[4], aB[4], bA[4], bB[4];

    // prologue: stage chunk 0, prime B ring
    STAGE_LOAD(0);
    LOAD_B(0, bA);
    LOAD_B(1, bB);
    STAGE_WRITE(0);
    __syncthreads();

    for (int cs = 0; cs < 8; ++cs) {
        const int buf = cs & 1;
        if (cs < 7) STAGE_LOAD(cs + 1);          // next chunk's x loads in flight
        LOAD_A(buf, 0, aA);
        LOAD_A(buf, 1, aB);
        #pragma unroll
        for (int j = 0; j < 8; j += 2) {
            const int S = cs * 8 + j;
            __builtin_amdgcn_s_setprio(1);
            DO_MFMA(aA, bA);
            __builtin_amdgcn_s_setprio(0);
            if (j < 6) LOAD_A(buf, j + 2, aA);
            LOAD_B((S + 2) & 63, bA);
            __builtin_amdgcn_s_setprio(1);
            DO_MFMA(aB, bB);
            __builtin_amdgcn_s_setprio(0);
            if (j < 6) LOAD_A(buf, j + 3, aB);
            LOAD_B((S + 3) & 63, bB);
        }
        if (cs < 7) STAGE_WRITE(buf ^ 1);
        __syncthreads();
    }

    // epilogue: + cnt(t)*256*bias; C/D map col=l16 (f), row=q*4+r
    #pragma unroll
    for (int mf = 0; mf < 4; ++mf) {
        #pragma unroll
        for (int nf = 0; nf < 4; ++nf) {
            const int f = ft * 64 + nf * 16 + l16;
            #pragma unroll
            for (int r = 0; r < 4; ++r) {
                const int t = t0 + w * 64 + mf * 16 + q * 4 + r;
                const int jmin = (t < T_ - SH) ? 0 : (((t - (T_ - SH)) >> 2) + 1);
                out[(size_t)(b * T_ + t) * F_ + f] =
                    acc[mf][nf][r] + (float)(8 - jmin) * 256.0f * bf4[nf];
            }
        }
    }
#undef STAGE_LOAD
#undef STAGE_WRITE
#undef LOAD_A
#undef LOAD_B
#undef DO_MFMA
}

extern "C" void kernel_launch(void* const* d_in, const int* in_sizes, int n_in,
                              void* d_out, int out_size, void* d_ws, size_t ws_size,
                              hipStream_t stream) {
    const float* x    = (const float*)d_in[0];
    const float* W    = (const float*)d_in[1];   // (C,KT,F)
    const float* bias = (const float*)d_in[2];
    float* out = (float*)d_out;
    ushort* Wf = (ushort*)d_ws;                  // 1 MiB scratch

    wprep_kernel<<<256, 256, 0, stream>>>(W, Wf);
    deconv_kernel<<<512, 256, 0, stream>>>(x, Wf, bias, out);
}

// Round 10
// 44.429 us; speedup vs baseline: 1.0091x; 1.0091x over previous
//
#include <hip/hip_runtime.h>
#include <hip/hip_bf16.h>

// MyDeConv1D as GEMM: out[b,t,f] = sum_{j,c} x[b,t+28-4j,c]*W[c,j,f] + cnt(t)*256*bias[f]
// M=32768, N=256, K=2048, bf16 MFMA 16x16x32.
// R10 = R9 traffic shape (block 256r x 64f, W_m=4, B block-broadcast, A-LDS x1)
//  + FIXED swizzle slot = g ^ ((row>>1)&3)  (bank-walked: exact 2-way = free)
//  + T3-style interleave: per tap {issue B(S+2) -> issue A(j+1) -> 1 stage-load
//    or stage-write -> setprio MFMA x16}, phase-stable depth-4 B ring (8%4==0),
//    depth-2 A ring, staging spread across taps (load@k, write@k+3).

#define B_    16
#define T_    2048
#define C_    256
#define KT    8
#define F_    256
#define SH    28
#define BT    256
#define ROWS  (BT + SH)        // 284
#define CH    32               // channels per chunk
#define CHW   (ROWS * CH)      // 9088 ushorts per buffer
#define NTASK (ROWS * 4)       // 1136 16B-granule staging tasks per chunk

typedef __attribute__((ext_vector_type(8))) short short8;
typedef __attribute__((ext_vector_type(4))) float floatx4;

// Wf frag order: fid = S*16 + g, S = cs*8 + j (cs: 32-ch chunk, j: tap).
// frag (S,g): lane(l16,q) holds B[k=q*8+i][f=g*16+l16], c = cs*32 + q*8 + i.
__global__ __launch_bounds__(256) void wprep_kernel(const float* __restrict__ W,
                                                    ushort* __restrict__ Wf) {
    const int tid  = threadIdx.x;
    const int fid  = blockIdx.x * 4 + (tid >> 6);   // 0..1023
    const int lane = tid & 63;
    const int g    = fid & 15;
    const int S    = fid >> 4;
    const int j    = S & 7, cs = S >> 3;
    const int c0   = cs * 32 + (lane >> 4) * 8;
    const int f    = g * 16 + (lane & 15);
    short8 pk;
    #pragma unroll
    for (int i = 0; i < 8; ++i) {
        __hip_bfloat16 h = __float2bfloat16(W[((c0 + i) * KT + j) * F_ + f]);
        pk[i] = *reinterpret_cast<const short*>(&h);
    }
    *reinterpret_cast<short8*>(Wf + (size_t)fid * 512 + lane * 8) = pk;
}

__device__ inline short8 cvt8(float4 a, float4 b) {
    float v[8] = {a.x, a.y, a.z, a.w, b.x, b.y, b.z, b.w};
    short8 r;
    #pragma unroll
    for (int i = 0; i < 8; ++i) {
        __hip_bfloat16 h = __float2bfloat16(v[i]);
        r[i] = *reinterpret_cast<const short*>(&h);
    }
    return r;
}

__global__ __launch_bounds__(256, 2) void deconv_kernel(
        const float* __restrict__ x, const ushort* __restrict__ Wf,
        const float* __restrict__ bias, float* __restrict__ out) {
    __shared__ ushort xs[2 * CHW];                  // 35.5 KiB
    const int bid  = blockIdx.x;
    const int ft   = bid >> 7;                      // f-tile 0..3
    const int tb   = bid & 127;
    const int b    = tb >> 3;
    const int t0   = (tb & 7) * BT;
    const int tid  = threadIdx.x;
    const int lane = tid & 63, w = tid >> 6;        // wave owns rows [w*64, w*64+64)
    const int l16  = lane & 15, q = lane >> 4;

    float4 SA[5], SB[5];

#define STAGE_LOAD_K(cs_, k_) do {                                             \
        const int task_ = tid + (k_) * 256;                                    \
        const int row_  = task_ >> 2, g_ = task_ & 3;                          \
        SA[k_] = make_float4(0.f, 0.f, 0.f, 0.f);                              \
        SB[k_] = make_float4(0.f, 0.f, 0.f, 0.f);                              \
        if (task_ < NTASK && t0 + row_ < T_) {                                 \
            const float4* p_ = reinterpret_cast<const float4*>(                \
                x + ((size_t)(b * T_ + t0 + row_) * C_ + (cs_) * CH + g_ * 8));\
            SA[k_] = p_[0]; SB[k_] = p_[1];                                    \
        } } while (0)

#define STAGE_WRITE_K(buf_, k_) do {                                           \
        const int task_ = tid + (k_) * 256;                                    \
        const int row_  = task_ >> 2, g_ = task_ & 3;                          \
        if (task_ < NTASK) {                                                   \
            const int sl_ = g_ ^ ((row_ >> 1) & 3);                            \
            *reinterpret_cast<short8*>(                                        \
                xs + (buf_) * CHW + row_ * CH + sl_ * 8) =                     \
                cvt8(SA[k_], SB[k_]);                                          \
        } } while (0)

    // A frag (tap j, frag mf): row = SH-4j + w*64 + mf*16 + l16 (<=283),
    // logical granule q, phys slot = q ^ ((row>>1)&3).
#define LOAD_A(buf_, j_, arr) do {                                             \
        const int rb_ = SH - 4 * (j_) + w * 64 + l16;                          \
        _Pragma("unroll")                                                      \
        for (int mf = 0; mf < 4; ++mf) {                                       \
            const int row_ = rb_ + mf * 16;                                    \
            const int sl_  = q ^ ((row_ >> 1) & 3);                            \
            arr[mf] = *reinterpret_cast<const short8*>(                        \
                xs + (buf_) * CHW + row_ * CH + sl_ * 8);                      \
        } } while (0)

#define LOAD_B(S_, arr) do {                                                   \
        const ushort* p_ = wbase + (size_t)(S_) * 8192;                        \
        _Pragma("unroll")                                                      \
        for (int nf = 0; nf < 4; ++nf)                                         \
            arr[nf] = *reinterpret_cast<const short8*>(p_ + nf * 512);         \
        } while (0)

#define DO_MFMA(aa, bb) do {                                                   \
        _Pragma("unroll")                                                      \
        for (int mf = 0; mf < 4; ++mf)                                         \
            _Pragma("unroll")                                                  \
            for (int nf = 0; nf < 4; ++nf)                                     \
                acc[mf][nf] = __builtin_amdgcn_mfma_f32_16x16x32_bf16(         \
                    aa[mf], bb[nf], acc[mf][nf], 0, 0, 0);                     \
        } while (0)

    // all 4 waves share wbase -> block-broadcast B (L1 reuse)
    const ushort* wbase = Wf + (size_t)(ft * 4) * 512 + lane * 8;

    float bf4[4];
    #pragma unroll
    for (int nf = 0; nf < 4; ++nf) bf4[nf] = bias[ft * 64 + nf * 16 + l16];

    floatx4 acc[4][4];
    #pragma unroll
    for (int mf = 0; mf < 4; ++mf)
        #pragma unroll
        for (int nf = 0; nf < 4; ++nf)
            acc[mf][nf] = (floatx4){0.f, 0.f, 0.f, 0.f};

    short8 aR[2][4];                // depth-2 A ring
    short8 bR[4][4];                // depth-4 B ring (phase-stable: 8 taps % 4 == 0)

    // ---- prologue: stage chunk 0, prime B(0),B(1) ----
    STAGE_LOAD_K(0, 0); STAGE_LOAD_K(0, 1); STAGE_LOAD_K(0, 2);
    STAGE_LOAD_K(0, 3); STAGE_LOAD_K(0, 4);
    LOAD_B(0, bR[0]);
    LOAD_B(1, bR[1]);
    STAGE_WRITE_K(0, 0); STAGE_WRITE_K(0, 1); STAGE_WRITE_K(0, 2);
    STAGE_WRITE_K(0, 3); STAGE_WRITE_K(0, 4);
    __syncthreads();
    LOAD_A(0, 0, aR[0]);

    for (int cs = 0; cs < 8; ++cs) {
        const int buf = cs & 1;
        const int Sb  = cs * 8;
        #pragma unroll
        for (int j = 0; j < 8; ++j) {
            LOAD_B((Sb + j + 2) & 63, bR[(j + 2) & 3]);   // consumed 2 taps later
            if (j < 7) LOAD_A(buf, j + 1, aR[(j + 1) & 1]);
            if (j < 5 && cs < 7) STAGE_LOAD_K(cs + 1, j); // 1 task group / tap
            if (j >= 3 && cs < 7) STAGE_WRITE_K(buf ^ 1, j - 3);
            __builtin_amdgcn_s_setprio(1);
            DO_MFMA(aR[j & 1], bR[j & 3]);
            __builtin_amdgcn_s_setprio(0);
        }
        __syncthreads();
        if (cs < 7) LOAD_A(buf ^ 1, 0, aR[0]);
    }

    // epilogue: + cnt(t)*256*bias; C/D map col=l16 (f), row=q*4+r
    #pragma unroll
    for (int mf = 0; mf < 4; ++mf) {
        #pragma unroll
        for (int nf = 0; nf < 4; ++nf) {
            const int f = ft * 64 + nf * 16 + l16;
            #pragma unroll
            for (int r = 0; r < 4; ++r) {
                const int t = t0 + w * 64 + mf * 16 + q * 4 + r;
                const int jmin = (t < T_ - SH) ? 0 : (((t - (T_ - SH)) >> 2) + 1);
                out[(size_t)(b * T_ + t) * F_ + f] =
                    acc[mf][nf][r] + (float)(8 - jmin) * 256.0f * bf4[nf];
            }
        }
    }
#undef STAGE_LOAD_K
#undef STAGE_WRITE_K
#undef LOAD_A
#undef LOAD_B
#undef DO_MFMA
}

extern "C" void kernel_launch(void* const* d_in, const int* in_sizes, int n_in,
                              void* d_out, int out_size, void* d_ws, size_t ws_size,
                              hipStream_t stream) {
    const float* x    = (const float*)d_in[0];
    const float* W    = (const float*)d_in[1];   // (C,KT,F)
    const float* bias = (const float*)d_in[2];
    float* out = (float*)d_out;
    ushort* Wf = (ushort*)d_ws;                  // 1 MiB scratch

    wprep_kernel<<<256, 256, 0, stream>>>(W, Wf);
    deconv_kernel<<<512, 256, 0, stream>>>(x, Wf, bias, out);
}